// Round 1
// 414.363 us; speedup vs baseline: 1.0266x; 1.0266x over previous
//
#include <hip/hip_runtime.h>
#include <math.h>

// Problem constants (match reference)
#define BB 4
#define NN 2048
#define CC 64
#define HH 512
#define WW 512
#define GS 8
#define HG 64
#define WG 64
#define MM 4096          // HG*WG
#define EPSF 1e-8f
#define NUM_NEG 4
#define MARGINF 1.0f

#define POOL_BLOCKS 512   // (b, gy, x-half) : 4*64*2
#define POS_BLOCKS  2048  // 4 kps per block

typedef __attribute__((ext_vector_type(8))) short short8;   // 8 bf16 (4 VGPRs)
typedef __attribute__((ext_vector_type(4))) float f32x4;

__device__ __forceinline__ unsigned short f32_to_bf16_rne(float x) {
    unsigned int u = __float_as_uint(x);
    u += 0x7fffu + ((u >> 16) & 1u);
    return (unsigned short)(u >> 16);
}

// Sorted-4 insert via v_med3_f32: 4 ops instead of 7 min/max.
// t0<=t1<=t2<=t3 invariant; exact order statistics of {t0..t3, v}.
__device__ __forceinline__ void ins4(float& t0, float& t1, float& t2, float& t3, float v) {
    t3 = __builtin_amdgcn_fmed3f(t2, t3, v);   // uses old t2
    t2 = __builtin_amdgcn_fmed3f(t1, t2, v);   // uses old t1
    t1 = __builtin_amdgcn_fmed3f(t0, t1, v);   // uses old t0
    t0 = fminf(t0, v);
}

// ---------------------------------------------------------------------------
// Kernel 1 (fused): blocks [0,512): avg-pool 8x8 + L2-normalize -> cells_bf, cn
//                   blocks [512,2560): bilinear positives -> dpos, an, kp_bf
// The pool half is HBM-BW-bound streaming; the pos half is latency-bound
// gather — co-resident they overlap instead of serializing.
// ---------------------------------------------------------------------------
__global__ __launch_bounds__(256) void prep_kernel(const float* __restrict__ desc2,
                                                   const float* __restrict__ w_kp1,
                                                   const float* __restrict__ kp1_desc,
                                                   unsigned short* __restrict__ cells_bf,
                                                   float* __restrict__ cn,
                                                   float* __restrict__ dpos,
                                                   float* __restrict__ an,
                                                   unsigned short* __restrict__ kp_bf) {
    __shared__ float smem[64][33];    // [channel][cell-in-block], +1 pad: 2-way banks (free)
    int tid  = threadIdx.x;
    int w    = tid >> 6;
    int lane = tid & 63;

    if (blockIdx.x < POOL_BLOCKS) {
        // ---- pool + normalize: block = (b, gy, xh) covers 32 cells x 64 ch ----
        int pb = blockIdx.x;
        int xh = pb & 1;
        int gy = (pb >> 1) & 63;
        int b  = pb >> 7;
        for (int ci = 0; ci < 16; ++ci) {
            int c = ci * 4 + w;
            const float* base = desc2
                + (((size_t)(b * CC + c) * HH + (size_t)gy * GS) * WW)
                + (size_t)xh * 256 + (size_t)lane * 4;
            float s = 0.f;
#pragma unroll
            for (int yy = 0; yy < GS; ++yy) {
                float4 a = *(const float4*)(base + (size_t)yy * WW);  // wave reads 1KB/row, coalesced
                s += a.x + a.y + a.z + a.w;
            }
            s += __shfl_xor(s, 1, 64);                 // combine lane pairs -> full 8x8 cell
            if (!(lane & 1)) smem[c][lane >> 1] = s * (1.0f / 64.0f);
        }
        __syncthreads();
        // normalize: wave w owns cells w*8..w*8+7; lane = channel
#pragma unroll
        for (int k = 0; k < 8; ++k) {
            int cell = w * 8 + k;
            float v = smem[lane][cell];
            float ss = v * v;
#pragma unroll
            for (int off = 32; off; off >>= 1) ss += __shfl_xor(ss, off, 64);
            float norm = sqrtf(ss);
            float inv = 1.0f / (norm + EPSF);
            int cellg = gy * WG + xh * 32 + cell;
            size_t o = ((size_t)b * MM + cellg) * CC + lane;
            cells_bf[o] = f32_to_bf16_rne(v * inv);    // 128B per wave, coalesced
            if (lane == 0) {
                float r = norm * inv;
                cn[(size_t)b * MM + cellg] = r * r;
            }
        }
    } else {
        // ---- bilinear-sample positives: one wave per keypoint; lane = channel ----
        int kp = (blockIdx.x - POOL_BLOCKS) * 4 + w;   // b*N + n
        int b = kp >> 11;                              // / N
        float wx = w_kp1[(size_t)kp * 2 + 0];
        float wy = w_kp1[(size_t)kp * 2 + 1];
        float x = fminf(fmaxf(wx, 0.f), (float)(WW - 1));
        float y = fminf(fmaxf(wy, 0.f), (float)(HH - 1));
        float x0 = floorf(x), y0 = floorf(y);
        int x0i = (int)x0, y0i = (int)y0;
        int x1i = min(x0i + 1, WW - 1);
        int y1i = min(y0i + 1, HH - 1);
        float fx = x - x0, fy = y - y0;
        const float* p = desc2 + ((size_t)b * CC + lane) * (size_t)HH * WW;
        float v00 = p[(size_t)y0i * WW + x0i];
        float v01 = p[(size_t)y0i * WW + x1i];
        float v10 = p[(size_t)y1i * WW + x0i];
        float v11 = p[(size_t)y1i * WW + x1i];
        float pos = (1.f - fy) * (1.f - fx) * v00 + (1.f - fy) * fx * v01
                  + fy * (1.f - fx) * v10 + fy * fx * v11;
        float ss = pos * pos;
#pragma unroll
        for (int off = 32; off; off >>= 1) ss += __shfl_xor(ss, off, 64);
        float posn = pos / (sqrtf(ss) + EPSF);
        float kd = kp1_desc[(size_t)kp * CC + lane];
        kp_bf[(size_t)kp * CC + lane] = f32_to_bf16_rne(kd);
        float diff = kd - posn;
        float dd = diff * diff;
        float aa = kd * kd;
#pragma unroll
        for (int off = 32; off; off >>= 1) {
            dd += __shfl_xor(dd, off, 64);
            aa += __shfl_xor(aa, off, 64);
        }
        if (lane == 0) {
            dpos[kp] = sqrtf(dd + EPSF);
            an[kp] = aa;
        }
    }
}

// ---------------------------------------------------------------------------
// Kernel 2: MFMA distance matrix + mask + per-partition top-4 (in d^2 space).
// Block = 4 waves = 64 kps; each wave: 16 kps x 512-cell partition.
// Per 16x16 tile: 2x v_mfma_f32_16x16x32_bf16 (K=64) + fp32 epilogue.
// D layout: col = lane&15 (cell), row = (lane>>4)*4 + reg (kp)  [m89/m91].
// ---------------------------------------------------------------------------
__global__ __launch_bounds__(256) void loss_mfma_kernel(const unsigned short* __restrict__ cells_bf,
                                                        const float* __restrict__ cn,
                                                        const unsigned short* __restrict__ kp_bf,
                                                        const float* __restrict__ w_kp1,
                                                        const float* __restrict__ an,
                                                        float* __restrict__ cand) {
    __shared__ float mg[4][16][16][4];   // [wave][kp_local][cell-lane][4] = 16 KB

    int b   = blockIdx.y;
    int kpg = blockIdx.x >> 3;           // 0..31  (group of 64 kps)
    int p   = blockIdx.x & 7;            // cell partition 0..7 (512 cells each)
    int tid = threadIdx.x;
    int w   = tid >> 6;                  // wave 0..3
    int L   = tid & 63;
    int q   = L >> 4;                    // quad
    int r   = L & 15;

    int n0 = kpg * 64 + w * 16;          // kp-tile base (within batch)

    const short8* arow = (const short8*)(kp_bf + (size_t)(b * NN + n0 + r) * CC);
    short8 afrag0 = arow[q];
    short8 afrag1 = arow[q + 4];

    const float4* anp = (const float4*)(an + (size_t)b * NN + n0 + q * 4);
    float4 an4 = anp[0];
    const float4* wp = (const float4*)(w_kp1 + (size_t)(b * NN + n0 + q * 4) * 2);
    float4 wA = wp[0], wB = wp[1];
    float wx0 = wA.x, wy0 = wA.y, wx1 = wA.z, wy1 = wA.w;
    float wx2 = wB.x, wy2 = wB.y, wx3 = wB.z, wy3 = wB.w;

    float t00 = 1e30f, t01 = 1e30f, t02 = 1e30f, t03 = 1e30f;
    float t10 = 1e30f, t11 = 1e30f, t12 = 1e30f, t13 = 1e30f;
    float t20 = 1e30f, t21 = 1e30f, t22 = 1e30f, t23 = 1e30f;
    float t30 = 1e30f, t31 = 1e30f, t32 = 1e30f, t33 = 1e30f;

    const unsigned short* cellb = cells_bf + (size_t)b * MM * CC;
    const float* cnb = cn + (size_t)b * MM;

#pragma unroll 4
    for (int t = 0; t < 32; ++t) {
        int m0 = p * 512 + t * 16;
        const short8* brow = (const short8*)(cellb + (size_t)(m0 + r) * CC);
        short8 bfrag0 = brow[q];
        short8 bfrag1 = brow[q + 4];
        float cnl = cnb[m0 + r];
        float cxl = (float)(((m0 & 63) + r) * 8 + 4);
        float cyl = (float)((m0 >> 6) * 8 + 4);

        f32x4 acc = {0.f, 0.f, 0.f, 0.f};
        acc = __builtin_amdgcn_mfma_f32_16x16x32_bf16(afrag0, bfrag0, acc, 0, 0, 0);
        acc = __builtin_amdgcn_mfma_f32_16x16x32_bf16(afrag1, bfrag1, acc, 0, 0, 0);

        // reg j -> kp n0 + q*4 + j, cell m0 + r  (mask arithmetic kept bitwise-identical)
        {
            float d2 = fmaf(-2.f, acc[0], an4.x + cnl);
            float dx = wx0 - cxl, dy = wy0 - cyl;
            float v = (fmaf(dx, dx, dy * dy) <= 64.f) ? 1e12f : d2;
            ins4(t00, t01, t02, t03, v);
        }
        {
            float d2 = fmaf(-2.f, acc[1], an4.y + cnl);
            float dx = wx1 - cxl, dy = wy1 - cyl;
            float v = (fmaf(dx, dx, dy * dy) <= 64.f) ? 1e12f : d2;
            ins4(t10, t11, t12, t13, v);
        }
        {
            float d2 = fmaf(-2.f, acc[2], an4.z + cnl);
            float dx = wx2 - cxl, dy = wy2 - cyl;
            float v = (fmaf(dx, dx, dy * dy) <= 64.f) ? 1e12f : d2;
            ins4(t20, t21, t22, t23, v);
        }
        {
            float d2 = fmaf(-2.f, acc[3], an4.w + cnl);
            float dx = wx3 - cxl, dy = wy3 - cyl;
            float v = (fmaf(dx, dx, dy * dy) <= 64.f) ? 1e12f : d2;
            ins4(t30, t31, t32, t33, v);
        }
    }

    // stash per-lane top4 lists: kp_local = q*4+j, cell-class = r
    {
        float4 v;
        v.x = t00; v.y = t01; v.z = t02; v.w = t03;
        *(float4*)&mg[w][q * 4 + 0][r][0] = v;
        v.x = t10; v.y = t11; v.z = t12; v.w = t13;
        *(float4*)&mg[w][q * 4 + 1][r][0] = v;
        v.x = t20; v.y = t21; v.z = t22; v.w = t23;
        *(float4*)&mg[w][q * 4 + 2][r][0] = v;
        v.x = t30; v.y = t31; v.z = t32; v.w = t33;
        *(float4*)&mg[w][q * 4 + 3][r][0] = v;
    }
    __syncthreads();

    // merge 16 lists of 4 per (wave, kp_local): 4 threads each take 4 lists,
    // then butterfly-merge across the 4 threads.
    int w2  = tid >> 6;
    int kl  = (tid >> 2) & 15;
    int seg = tid & 3;
    float m0v = 1e30f, m1v = 1e30f, m2v = 1e30f, m3v = 1e30f;
#pragma unroll
    for (int i = 0; i < 4; ++i) {
        float4 v = *(const float4*)&mg[w2][kl][seg * 4 + i][0];
        ins4(m0v, m1v, m2v, m3v, v.x);
        ins4(m0v, m1v, m2v, m3v, v.y);
        ins4(m0v, m1v, m2v, m3v, v.z);
        ins4(m0v, m1v, m2v, m3v, v.w);
    }
#pragma unroll
    for (int step = 1; step <= 2; step <<= 1) {
        float p0 = __shfl_xor(m0v, step, 64);
        float p1 = __shfl_xor(m1v, step, 64);
        float p2 = __shfl_xor(m2v, step, 64);
        float p3 = __shfl_xor(m3v, step, 64);
        ins4(m0v, m1v, m2v, m3v, p0);
        ins4(m0v, m1v, m2v, m3v, p1);
        ins4(m0v, m1v, m2v, m3v, p2);
        ins4(m0v, m1v, m2v, m3v, p3);
    }
    if (seg == 0) {
        size_t kp = (size_t)b * NN + kpg * 64 + w2 * 16 + kl;
        float4 v; v.x = m0v; v.y = m1v; v.z = m2v; v.w = m3v;
        *(float4*)(cand + kp * 32 + p * 4) = v;
    }
}

// ---------------------------------------------------------------------------
// Kernel 3: per-kp merge of 8 partitions, sqrt, loss, block partial sums.
// ---------------------------------------------------------------------------
__global__ __launch_bounds__(256) void merge_kernel(const float* __restrict__ cand,
                                                    const float* __restrict__ dpos,
                                                    float* __restrict__ partials) {
    __shared__ float s4[4];
    int kp = blockIdx.x * 256 + threadIdx.x;
    float m0 = 1e30f, m1 = 1e30f, m2 = 1e30f, m3 = 1e30f;
    const float4* cp = (const float4*)(cand + (size_t)kp * 32);
#pragma unroll
    for (int i = 0; i < 8; ++i) {
        float4 v = cp[i];
        ins4(m0, m1, m2, m3, v.x);
        ins4(m0, m1, m2, m3, v.y);
        ins4(m0, m1, m2, m3, v.z);
        ins4(m0, m1, m2, m3, v.w);
    }
    float dp = dpos[kp];
    float d0 = sqrtf(fmaxf(m0, 0.f) + EPSF);
    float d1 = sqrtf(fmaxf(m1, 0.f) + EPSF);
    float d2 = sqrtf(fmaxf(m2, 0.f) + EPSF);
    float d3 = sqrtf(fmaxf(m3, 0.f) + EPSF);
    float l = fmaxf(dp - d0 + MARGINF, 0.f)
            + fmaxf(dp - d1 + MARGINF, 0.f)
            + fmaxf(dp - d2 + MARGINF, 0.f)
            + fmaxf(dp - d3 + MARGINF, 0.f);
#pragma unroll
    for (int off = 32; off; off >>= 1) l += __shfl_xor(l, off, 64);
    if ((threadIdx.x & 63) == 0) s4[threadIdx.x >> 6] = l;
    __syncthreads();
    if (threadIdx.x == 0)
        partials[blockIdx.x] = s4[0] + s4[1] + s4[2] + s4[3];
}

// ---------------------------------------------------------------------------
// Kernel 4: reduce 32 block partials -> mean -> d_out[0]
// ---------------------------------------------------------------------------
__global__ __launch_bounds__(64) void finalize_kernel(const float* __restrict__ partials,
                                                      float* __restrict__ out) {
    int tid = threadIdx.x;
    float v = (tid < 32) ? partials[tid] : 0.f;
#pragma unroll
    for (int off = 32; off; off >>= 1) v += __shfl_xor(v, off, 64);
    if (tid == 0) out[0] = v * (1.0f / (float)(BB * NN * NUM_NEG));
}

extern "C" void kernel_launch(void* const* d_in, const int* in_sizes, int n_in,
                              void* d_out, int out_size, void* d_ws, size_t ws_size,
                              hipStream_t stream) {
    // inputs: 0=kp1 (unused), 1=w_kp1, 2=kp1_desc, 3=desc2, 4=homo12 (unused)
    const float* w_kp1    = (const float*)d_in[1];
    const float* kp1_desc = (const float*)d_in[2];
    const float* desc2    = (const float*)d_in[3];
    float* out = (float*)d_out;

    float* ws = (float*)d_ws;
    float* cn       = ws;                               // B*M     = 16,384 f
    float* dpos     = cn + (size_t)BB * MM;             // B*N     = 8,192 f
    float* an       = dpos + (size_t)BB * NN;           // B*N     = 8,192 f
    float* partials = an + (size_t)BB * NN;             // 32 f (pad to 64)
    float* cand     = partials + 64;                    // B*N*32  = 262,144 f
    unsigned short* cells_bf = (unsigned short*)(cand + (size_t)BB * NN * 32); // B*M*C bf16
    unsigned short* kp_bf    = cells_bf + (size_t)BB * MM * CC;                // B*N*C bf16

    prep_kernel<<<dim3(POOL_BLOCKS + POS_BLOCKS), dim3(256), 0, stream>>>(
        desc2, w_kp1, kp1_desc, cells_bf, cn, dpos, an, kp_bf);
    loss_mfma_kernel<<<dim3(256, BB), dim3(256), 0, stream>>>(
        cells_bf, cn, kp_bf, w_kp1, an, cand);
    merge_kernel<<<dim3(BB * NN / 256), dim3(256), 0, stream>>>(cand, dpos, partials);
    finalize_kernel<<<dim3(1), dim3(64), 0, stream>>>(partials, out);
}